// Round 4
// baseline (266.089 us; speedup 1.0000x reference)
//
#include <hip/hip_runtime.h>

#define NBINS 8192            // 13-bit top bits of sortable key
#define HIST_BLOCKS 2048
#define HIST_THREADS 256
#define SUM_BLOCKS 2048
#define SUM_THREADS 256

struct Control {
  float lo_f;     // smallest float in boundary bin
  float hi_f;     // smallest float in bin above boundary (inf if none)
  float frac;     // weight for boundary-bin elements
  unsigned bsel;  // boundary bin index (debug)
};

// Monotone float -> uint map (ascending). Larger curvature -> larger key.
__device__ __forceinline__ unsigned sortable_key(float f) {
  unsigned u = __float_as_uint(f);
  return u ^ ((u & 0x80000000u) ? 0xFFFFFFFFu : 0x80000000u);
}

// Inverse of sortable_key.
__device__ __forceinline__ float key_to_float(unsigned k) {
  unsigned u = (k & 0x80000000u) ? (k ^ 0x80000000u) : ~k;
  return __uint_as_float(u);
}

__device__ __forceinline__ unsigned agent_load_u32(const unsigned* p) {
  return __hip_atomic_load(p, __ATOMIC_RELAXED, __HIP_MEMORY_SCOPE_AGENT);
}
__device__ __forceinline__ float agent_load_f32(const float* p) {
  return __hip_atomic_load(p, __ATOMIC_RELAXED, __HIP_MEMORY_SCOPE_AGENT);
}

// Pass 1: 13-bit histogram of curvature keys. Last block to finish also
// performs the threshold selection (suffix scan from the top) and writes ctl.
__global__ void __launch_bounds__(HIST_THREADS) hist_kernel(
    const float* __restrict__ cv, unsigned* __restrict__ hist,
    Control* __restrict__ ctl, unsigned* __restrict__ done,
    int nvec, int ntail, unsigned K) {
  __shared__ unsigned h[NBINS];
  for (int i = threadIdx.x; i < NBINS; i += HIST_THREADS) h[i] = 0;
  __syncthreads();

  const float4* __restrict__ c4 = (const float4*)cv;
  int idx = blockIdx.x * HIST_THREADS + threadIdx.x;
  int stride = gridDim.x * HIST_THREADS;
  int i = idx;
  for (; i + 3 * stride < nvec; i += 4 * stride) {  // 4 loads in flight
    float4 v0 = c4[i];
    float4 v1 = c4[i + stride];
    float4 v2 = c4[i + 2 * stride];
    float4 v3 = c4[i + 3 * stride];
    atomicAdd(&h[sortable_key(v0.x) >> 19], 1u);
    atomicAdd(&h[sortable_key(v0.y) >> 19], 1u);
    atomicAdd(&h[sortable_key(v0.z) >> 19], 1u);
    atomicAdd(&h[sortable_key(v0.w) >> 19], 1u);
    atomicAdd(&h[sortable_key(v1.x) >> 19], 1u);
    atomicAdd(&h[sortable_key(v1.y) >> 19], 1u);
    atomicAdd(&h[sortable_key(v1.z) >> 19], 1u);
    atomicAdd(&h[sortable_key(v1.w) >> 19], 1u);
    atomicAdd(&h[sortable_key(v2.x) >> 19], 1u);
    atomicAdd(&h[sortable_key(v2.y) >> 19], 1u);
    atomicAdd(&h[sortable_key(v2.z) >> 19], 1u);
    atomicAdd(&h[sortable_key(v2.w) >> 19], 1u);
    atomicAdd(&h[sortable_key(v3.x) >> 19], 1u);
    atomicAdd(&h[sortable_key(v3.y) >> 19], 1u);
    atomicAdd(&h[sortable_key(v3.z) >> 19], 1u);
    atomicAdd(&h[sortable_key(v3.w) >> 19], 1u);
  }
  for (; i < nvec; i += stride) {
    float4 v = c4[i];
    atomicAdd(&h[sortable_key(v.x) >> 19], 1u);
    atomicAdd(&h[sortable_key(v.y) >> 19], 1u);
    atomicAdd(&h[sortable_key(v.z) >> 19], 1u);
    atomicAdd(&h[sortable_key(v.w) >> 19], 1u);
  }
  if (idx == 0) {  // scalar tail -> global hist directly
    for (int e = nvec * 4; e < nvec * 4 + ntail; ++e)
      atomicAdd(&hist[sortable_key(cv[e]) >> 19], 1u);
  }
  __syncthreads();
  for (int b = threadIdx.x; b < NBINS; b += HIST_THREADS) {
    unsigned c = h[b];
    if (c) atomicAdd(&hist[b], c);  // most bins empty -> skip
  }

  // last-block pattern: the final block performs selection
  __threadfence();
  __syncthreads();
  __shared__ unsigned lastFlag;
  if (threadIdx.x == 0) {
    unsigned old = atomicAdd(done, 1u);
    lastFlag = (old == (unsigned)gridDim.x - 1u) ? 1u : 0u;
  }
  __syncthreads();
  if (!lastFlag) return;

  // ---- selection: suffix scan from highest bin, find K crossing ----
  int tid = threadIdx.x;
  int lane = tid & 63;
  int wid = tid >> 6;
  unsigned base = (unsigned)tid * 32u;  // 256 threads x 32 bins
  unsigned c[32];
  unsigned cs = 0;
#pragma unroll
  for (int j = 0; j < 32; ++j) {
    c[j] = agent_load_u32(&hist[base + j]);
    cs += c[j];
  }
  // wave inclusive suffix sum of chunk totals
  unsigned incl = cs;
#pragma unroll
  for (int off = 1; off < 64; off <<= 1) {
    unsigned o = __shfl_down(incl, off);
    if (lane + off < 64) incl += o;
  }
  __shared__ unsigned waveTot[4];
  __shared__ unsigned waveSuf[4];
  if (lane == 0) waveTot[wid] = incl;
  __syncthreads();
  if (tid == 0) {
    unsigned run = 0;
    for (int w = 3; w >= 0; --w) { waveSuf[w] = run; run += waveTot[w]; }
  }
  __syncthreads();

  unsigned run = waveSuf[wid] + (incl - cs);  // count strictly above my chunk
#pragma unroll
  for (int j = 31; j >= 0; --j) {  // high -> low
    unsigned cc = c[j];
    if (cc && run < K && run + cc >= K) {  // unique crossing
      unsigned b = base + (unsigned)j;
      ctl->bsel = b;
      ctl->frac = (float)((double)(K - run) / (double)cc);
      ctl->lo_f = key_to_float(b << 19);
      ctl->hi_f = (b == NBINS - 1u) ? __uint_as_float(0x7F800000u)
                                    : key_to_float((b + 1u) << 19);
    }
    run += cc;
  }
}

// Pass 2: weighted sums with float-threshold classification; per-block
// partials to distinct slots; last block reduces and writes the loss.
__global__ void __launch_bounds__(SUM_THREADS) sum_kernel(
    const float* __restrict__ xin, const float* __restrict__ tin,
    const float* __restrict__ cin, const Control* __restrict__ ctl,
    float* __restrict__ partials, unsigned* __restrict__ done,
    float* __restrict__ out, int nvec, int ntail) {
  const float lo = ctl->lo_f;
  const float hi = ctl->hi_f;
  const float frac = ctl->frac;

  const float4* __restrict__ x4 = (const float4*)xin;
  const float4* __restrict__ t4 = (const float4*)tin;
  const float4* __restrict__ c4 = (const float4*)cin;

  float sp = 0.f, st = 0.f, spt = 0.f;
  int idx = blockIdx.x * SUM_THREADS + threadIdx.x;
  int stride = gridDim.x * SUM_THREADS;
  int i = idx;
  for (; i + 3 * stride < nvec; i += 4 * stride) {  // 12 loads in flight
    float4 c0 = c4[i];
    float4 c1 = c4[i + stride];
    float4 c2 = c4[i + 2 * stride];
    float4 c3 = c4[i + 3 * stride];
    float4 x0 = x4[i];
    float4 x1 = x4[i + stride];
    float4 x2 = x4[i + 2 * stride];
    float4 x3 = x4[i + 3 * stride];
    float4 t0 = t4[i];
    float4 t1 = t4[i + stride];
    float4 t2 = t4[i + 2 * stride];
    float4 t3 = t4[i + 3 * stride];
#pragma unroll
    for (int j = 0; j < 4; ++j) {
      float cj = (&c0.x)[j], xj = (&x0.x)[j], tj = (&t0.x)[j];
      float w = (cj >= hi) ? 1.f : ((cj >= lo) ? frac : 0.f);
      float p = __fdividef(1.f, 1.f + __expf(-xj));
      sp += w * p; st += w * tj; spt += (w * p) * tj;
    }
#pragma unroll
    for (int j = 0; j < 4; ++j) {
      float cj = (&c1.x)[j], xj = (&x1.x)[j], tj = (&t1.x)[j];
      float w = (cj >= hi) ? 1.f : ((cj >= lo) ? frac : 0.f);
      float p = __fdividef(1.f, 1.f + __expf(-xj));
      sp += w * p; st += w * tj; spt += (w * p) * tj;
    }
#pragma unroll
    for (int j = 0; j < 4; ++j) {
      float cj = (&c2.x)[j], xj = (&x2.x)[j], tj = (&t2.x)[j];
      float w = (cj >= hi) ? 1.f : ((cj >= lo) ? frac : 0.f);
      float p = __fdividef(1.f, 1.f + __expf(-xj));
      sp += w * p; st += w * tj; spt += (w * p) * tj;
    }
#pragma unroll
    for (int j = 0; j < 4; ++j) {
      float cj = (&c3.x)[j], xj = (&x3.x)[j], tj = (&t3.x)[j];
      float w = (cj >= hi) ? 1.f : ((cj >= lo) ? frac : 0.f);
      float p = __fdividef(1.f, 1.f + __expf(-xj));
      sp += w * p; st += w * tj; spt += (w * p) * tj;
    }
  }
  for (; i < nvec; i += stride) {
    float4 cv = c4[i], xv = x4[i], tv = t4[i];
#pragma unroll
    for (int j = 0; j < 4; ++j) {
      float cj = (&cv.x)[j], xj = (&xv.x)[j], tj = (&tv.x)[j];
      float w = (cj >= hi) ? 1.f : ((cj >= lo) ? frac : 0.f);
      float p = __fdividef(1.f, 1.f + __expf(-xj));
      sp += w * p; st += w * tj; spt += (w * p) * tj;
    }
  }
  if (idx == 0) {  // scalar tail (N % 4)
    for (int e = nvec * 4; e < nvec * 4 + ntail; ++e) {
      float cj = cin[e];
      float w = (cj >= hi) ? 1.f : ((cj >= lo) ? frac : 0.f);
      float p = __fdividef(1.f, 1.f + __expf(-xin[e]));
      sp += w * p; st += w * tin[e]; spt += (w * p) * tin[e];
    }
  }

  // block reduction
#pragma unroll
  for (int off = 32; off > 0; off >>= 1) {
    sp  += __shfl_down(sp, off);
    st  += __shfl_down(st, off);
    spt += __shfl_down(spt, off);
  }
  __shared__ float wsum[3][SUM_THREADS / 64];
  int lane = threadIdx.x & 63;
  int wid = threadIdx.x >> 6;
  if (lane == 0) { wsum[0][wid] = sp; wsum[1][wid] = st; wsum[2][wid] = spt; }
  __syncthreads();
  __shared__ unsigned lastFlag;
  if (threadIdx.x == 0) {
    float a = 0.f, b = 0.f, c = 0.f;
#pragma unroll
    for (int w = 0; w < SUM_THREADS / 64; ++w) {
      a += wsum[0][w]; b += wsum[1][w]; c += wsum[2][w];
    }
    partials[blockIdx.x]                  = a;
    partials[SUM_BLOCKS + blockIdx.x]     = b;
    partials[2 * SUM_BLOCKS + blockIdx.x] = c;
    __threadfence();
    unsigned old = atomicAdd(done, 1u);
    lastFlag = (old == (unsigned)gridDim.x - 1u) ? 1u : 0u;
  }
  __syncthreads();
  if (!lastFlag) return;

  // ---- final deterministic f64 reduction (last block only) ----
  double a = 0, b = 0, c = 0;
  for (int j = threadIdx.x; j < SUM_BLOCKS; j += SUM_THREADS) {
    a += (double)agent_load_f32(&partials[j]);
    b += (double)agent_load_f32(&partials[SUM_BLOCKS + j]);
    c += (double)agent_load_f32(&partials[2 * SUM_BLOCKS + j]);
  }
#pragma unroll
  for (int off = 32; off > 0; off >>= 1) {
    a += __shfl_down(a, off);
    b += __shfl_down(b, off);
    c += __shfl_down(c, off);
  }
  __shared__ double dsum[3][SUM_THREADS / 64];
  if (lane == 0) { dsum[0][wid] = a; dsum[1][wid] = b; dsum[2][wid] = c; }
  __syncthreads();
  if (threadIdx.x == 0) {
    double A = 0, B = 0, C = 0;
#pragma unroll
    for (int w = 0; w < SUM_THREADS / 64; ++w) {
      A += dsum[0][w]; B += dsum[1][w]; C += dsum[2][w];
    }
    double dice = (2.0 * C + 1.0) / (A + B + 1.0);
    out[0] = (float)(1.0 - dice);
  }
}

extern "C" void kernel_launch(void* const* d_in, const int* in_sizes, int n_in,
                              void* d_out, int out_size, void* d_ws, size_t ws_size,
                              hipStream_t stream) {
  const float* d_inputs  = (const float*)d_in[0];
  const float* d_targets = (const float*)d_in[1];
  const float* d_curv    = (const float*)d_in[2];
  float* out = (float*)d_out;

  int N = in_sizes[2];
  unsigned K = (unsigned)(0.4 * (double)N);  // matches Python int(R*N)

  unsigned* hist   = (unsigned*)d_ws;                        // 32 KB
  Control* ctl     = (Control*)((char*)d_ws + 32768);        // 16 B
  unsigned* done0  = (unsigned*)((char*)d_ws + 32768 + 16);  // hist done ctr
  unsigned* done1  = (unsigned*)((char*)d_ws + 32768 + 20);  // sum done ctr
  float* partials  = (float*)((char*)d_ws + 32768 + 64);     // 3*SUM_BLOCKS f32

  // zero hist + ctl + done counters every call (graph-replay safe)
  hipMemsetAsync(d_ws, 0, 32768 + 64, stream);

  int nvec = N / 4;
  int ntail = N - nvec * 4;

  hist_kernel<<<HIST_BLOCKS, HIST_THREADS, 0, stream>>>(
      d_curv, hist, ctl, done0, nvec, ntail, K);
  sum_kernel<<<SUM_BLOCKS, SUM_THREADS, 0, stream>>>(
      d_inputs, d_targets, d_curv, ctl, partials, done1, out, nvec, ntail);
}

// Round 5
// 81.230 us; speedup vs baseline: 3.2758x; 3.2758x over previous
//
#include <hip/hip_runtime.h>

#define NBINS 8192            // 13-bit top bits of sortable key
#define HIST_BLOCKS 1024
#define HIST_THREADS 256
#define SUM_BLOCKS 2048
#define SUM_THREADS 256

struct Control {
  float lo_f;     // smallest float in boundary bin
  float hi_f;     // smallest float in bin above boundary (inf if none)
  float frac;     // weight for boundary-bin elements
  unsigned bsel;  // boundary bin index (debug)
};

// Monotone float -> uint map (ascending). Larger curvature -> larger key.
__device__ __forceinline__ unsigned sortable_key(float f) {
  unsigned u = __float_as_uint(f);
  return u ^ ((u & 0x80000000u) ? 0xFFFFFFFFu : 0x80000000u);
}

// Inverse of sortable_key.
__device__ __forceinline__ float key_to_float(unsigned k) {
  unsigned u = (k & 0x80000000u) ? (k ^ 0x80000000u) : ~k;
  return __uint_as_float(u);
}

// Pass 1: 13-bit LDS histogram of curvature keys, merged via global atomics.
// No fences, no cross-block signaling.
__global__ void __launch_bounds__(HIST_THREADS) hist_kernel(
    const float* __restrict__ cv, unsigned* __restrict__ hist,
    int nvec, int ntail) {
  __shared__ unsigned h[NBINS];
  for (int i = threadIdx.x; i < NBINS; i += HIST_THREADS) h[i] = 0;
  __syncthreads();

  const float4* __restrict__ c4 = (const float4*)cv;
  int idx = blockIdx.x * HIST_THREADS + threadIdx.x;
  int stride = gridDim.x * HIST_THREADS;
  int i = idx;
  for (; i + 3 * stride < nvec; i += 4 * stride) {  // 4 loads in flight
    float4 v0 = c4[i];
    float4 v1 = c4[i + stride];
    float4 v2 = c4[i + 2 * stride];
    float4 v3 = c4[i + 3 * stride];
    atomicAdd(&h[sortable_key(v0.x) >> 19], 1u);
    atomicAdd(&h[sortable_key(v0.y) >> 19], 1u);
    atomicAdd(&h[sortable_key(v0.z) >> 19], 1u);
    atomicAdd(&h[sortable_key(v0.w) >> 19], 1u);
    atomicAdd(&h[sortable_key(v1.x) >> 19], 1u);
    atomicAdd(&h[sortable_key(v1.y) >> 19], 1u);
    atomicAdd(&h[sortable_key(v1.z) >> 19], 1u);
    atomicAdd(&h[sortable_key(v1.w) >> 19], 1u);
    atomicAdd(&h[sortable_key(v2.x) >> 19], 1u);
    atomicAdd(&h[sortable_key(v2.y) >> 19], 1u);
    atomicAdd(&h[sortable_key(v2.z) >> 19], 1u);
    atomicAdd(&h[sortable_key(v2.w) >> 19], 1u);
    atomicAdd(&h[sortable_key(v3.x) >> 19], 1u);
    atomicAdd(&h[sortable_key(v3.y) >> 19], 1u);
    atomicAdd(&h[sortable_key(v3.z) >> 19], 1u);
    atomicAdd(&h[sortable_key(v3.w) >> 19], 1u);
  }
  for (; i < nvec; i += stride) {
    float4 v = c4[i];
    atomicAdd(&h[sortable_key(v.x) >> 19], 1u);
    atomicAdd(&h[sortable_key(v.y) >> 19], 1u);
    atomicAdd(&h[sortable_key(v.z) >> 19], 1u);
    atomicAdd(&h[sortable_key(v.w) >> 19], 1u);
  }
  if (idx == 0) {  // scalar tail -> global hist directly
    for (int e = nvec * 4; e < nvec * 4 + ntail; ++e)
      atomicAdd(&hist[sortable_key(cv[e]) >> 19], 1u);
  }
  __syncthreads();
  for (int b = threadIdx.x; b < NBINS; b += HIST_THREADS) {
    unsigned c = h[b];
    if (c) atomicAdd(&hist[b], c);  // most bins empty -> skip
  }
}

// One block, 256 threads x 32 bins each: suffix scan from the top, find the
// K crossing, emit float thresholds + boundary fraction.
__global__ void __launch_bounds__(256) select_kernel(
    const unsigned* __restrict__ hist, Control* __restrict__ ctl, unsigned K) {
  int tid = threadIdx.x;
  int lane = tid & 63;
  int wid = tid >> 6;
  unsigned base = (unsigned)tid * 32u;
  unsigned c[32];
  unsigned cs = 0;
#pragma unroll
  for (int j = 0; j < 32; ++j) { c[j] = hist[base + j]; cs += c[j]; }

  // wave inclusive suffix sum of chunk totals
  unsigned incl = cs;
#pragma unroll
  for (int off = 1; off < 64; off <<= 1) {
    unsigned o = __shfl_down(incl, off);
    if (lane + off < 64) incl += o;
  }
  __shared__ unsigned waveTot[4];
  __shared__ unsigned waveSuf[4];
  if (lane == 0) waveTot[wid] = incl;
  __syncthreads();
  if (tid == 0) {
    unsigned run = 0;
    for (int w = 3; w >= 0; --w) { waveSuf[w] = run; run += waveTot[w]; }
  }
  __syncthreads();

  unsigned run = waveSuf[wid] + (incl - cs);  // count strictly above my chunk
#pragma unroll
  for (int j = 31; j >= 0; --j) {  // high -> low
    unsigned cc = c[j];
    if (cc && run < K && run + cc >= K) {  // unique crossing
      unsigned b = base + (unsigned)j;
      ctl->bsel = b;
      ctl->frac = (float)((double)(K - run) / (double)cc);
      ctl->lo_f = key_to_float(b << 19);
      ctl->hi_f = (b == NBINS - 1u) ? __uint_as_float(0x7F800000u)
                                    : key_to_float((b + 1u) << 19);
    }
    run += cc;
  }
}

// Pass 2: weighted sums with float-threshold classification; per-block
// partials to distinct slots (no atomics, no fences).
__global__ void __launch_bounds__(SUM_THREADS) sum_kernel(
    const float* __restrict__ xin, const float* __restrict__ tin,
    const float* __restrict__ cin, const Control* __restrict__ ctl,
    float* __restrict__ partials,  // SoA: [3][SUM_BLOCKS]
    int nvec, int ntail) {
  const float lo = ctl->lo_f;
  const float hi = ctl->hi_f;
  const float frac = ctl->frac;

  const float4* __restrict__ x4 = (const float4*)xin;
  const float4* __restrict__ t4 = (const float4*)tin;
  const float4* __restrict__ c4 = (const float4*)cin;

  float sp = 0.f, st = 0.f, spt = 0.f;
  int idx = blockIdx.x * SUM_THREADS + threadIdx.x;
  int stride = gridDim.x * SUM_THREADS;
  int i = idx;
  for (; i + 3 * stride < nvec; i += 4 * stride) {  // 12 loads in flight
    float4 c0 = c4[i];
    float4 c1 = c4[i + stride];
    float4 c2 = c4[i + 2 * stride];
    float4 c3 = c4[i + 3 * stride];
    float4 x0 = x4[i];
    float4 x1 = x4[i + stride];
    float4 x2 = x4[i + 2 * stride];
    float4 x3 = x4[i + 3 * stride];
    float4 t0 = t4[i];
    float4 t1 = t4[i + stride];
    float4 t2 = t4[i + 2 * stride];
    float4 t3 = t4[i + 3 * stride];
#pragma unroll
    for (int j = 0; j < 4; ++j) {
      float cj = (&c0.x)[j], xj = (&x0.x)[j], tj = (&t0.x)[j];
      float w = (cj >= hi) ? 1.f : ((cj >= lo) ? frac : 0.f);
      float p = __fdividef(1.f, 1.f + __expf(-xj));
      sp += w * p; st += w * tj; spt += (w * p) * tj;
    }
#pragma unroll
    for (int j = 0; j < 4; ++j) {
      float cj = (&c1.x)[j], xj = (&x1.x)[j], tj = (&t1.x)[j];
      float w = (cj >= hi) ? 1.f : ((cj >= lo) ? frac : 0.f);
      float p = __fdividef(1.f, 1.f + __expf(-xj));
      sp += w * p; st += w * tj; spt += (w * p) * tj;
    }
#pragma unroll
    for (int j = 0; j < 4; ++j) {
      float cj = (&c2.x)[j], xj = (&x2.x)[j], tj = (&t2.x)[j];
      float w = (cj >= hi) ? 1.f : ((cj >= lo) ? frac : 0.f);
      float p = __fdividef(1.f, 1.f + __expf(-xj));
      sp += w * p; st += w * tj; spt += (w * p) * tj;
    }
#pragma unroll
    for (int j = 0; j < 4; ++j) {
      float cj = (&c3.x)[j], xj = (&x3.x)[j], tj = (&t3.x)[j];
      float w = (cj >= hi) ? 1.f : ((cj >= lo) ? frac : 0.f);
      float p = __fdividef(1.f, 1.f + __expf(-xj));
      sp += w * p; st += w * tj; spt += (w * p) * tj;
    }
  }
  for (; i < nvec; i += stride) {
    float4 cv = c4[i], xv = x4[i], tv = t4[i];
#pragma unroll
    for (int j = 0; j < 4; ++j) {
      float cj = (&cv.x)[j], xj = (&xv.x)[j], tj = (&tv.x)[j];
      float w = (cj >= hi) ? 1.f : ((cj >= lo) ? frac : 0.f);
      float p = __fdividef(1.f, 1.f + __expf(-xj));
      sp += w * p; st += w * tj; spt += (w * p) * tj;
    }
  }
  if (idx == 0) {  // scalar tail (N % 4)
    for (int e = nvec * 4; e < nvec * 4 + ntail; ++e) {
      float cj = cin[e];
      float w = (cj >= hi) ? 1.f : ((cj >= lo) ? frac : 0.f);
      float p = __fdividef(1.f, 1.f + __expf(-xin[e]));
      sp += w * p; st += w * tin[e]; spt += (w * p) * tin[e];
    }
  }

#pragma unroll
  for (int off = 32; off > 0; off >>= 1) {
    sp  += __shfl_down(sp, off);
    st  += __shfl_down(st, off);
    spt += __shfl_down(spt, off);
  }
  __shared__ float wsum[3][SUM_THREADS / 64];
  int lane = threadIdx.x & 63;
  int wid = threadIdx.x >> 6;
  if (lane == 0) { wsum[0][wid] = sp; wsum[1][wid] = st; wsum[2][wid] = spt; }
  __syncthreads();
  if (threadIdx.x == 0) {
    float a = 0.f, b = 0.f, c = 0.f;
#pragma unroll
    for (int w = 0; w < SUM_THREADS / 64; ++w) {
      a += wsum[0][w]; b += wsum[1][w]; c += wsum[2][w];
    }
    partials[blockIdx.x]                  = a;
    partials[SUM_BLOCKS + blockIdx.x]     = b;
    partials[2 * SUM_BLOCKS + blockIdx.x] = c;
  }
}

// Deterministic f64 reduction of per-block partials + dice.
__global__ void __launch_bounds__(1024) reduce_kernel(
    const float* __restrict__ partials, float* __restrict__ out) {
  __shared__ double wsum[3][16];
  int tid = threadIdx.x;
  int lane = tid & 63;
  int wid = tid >> 6;

  double sp = 0, st = 0, spt = 0;
  for (int j = tid; j < SUM_BLOCKS; j += 1024) {
    sp  += (double)partials[j];
    st  += (double)partials[SUM_BLOCKS + j];
    spt += (double)partials[2 * SUM_BLOCKS + j];
  }
#pragma unroll
  for (int off = 32; off > 0; off >>= 1) {
    sp  += __shfl_down(sp, off);
    st  += __shfl_down(st, off);
    spt += __shfl_down(spt, off);
  }
  if (lane == 0) { wsum[0][wid] = sp; wsum[1][wid] = st; wsum[2][wid] = spt; }
  __syncthreads();
  if (tid == 0) {
    double a = 0, b = 0, c = 0;
#pragma unroll
    for (int w = 0; w < 16; ++w) { a += wsum[0][w]; b += wsum[1][w]; c += wsum[2][w]; }
    double dice = (2.0 * c + 1.0) / (a + b + 1.0);
    out[0] = (float)(1.0 - dice);
  }
}

extern "C" void kernel_launch(void* const* d_in, const int* in_sizes, int n_in,
                              void* d_out, int out_size, void* d_ws, size_t ws_size,
                              hipStream_t stream) {
  const float* d_inputs  = (const float*)d_in[0];
  const float* d_targets = (const float*)d_in[1];
  const float* d_curv    = (const float*)d_in[2];
  float* out = (float*)d_out;

  int N = in_sizes[2];
  unsigned K = (unsigned)(0.4 * (double)N);  // matches Python int(R*N)

  unsigned* hist  = (unsigned*)d_ws;                      // 32 KB
  Control* ctl    = (Control*)((char*)d_ws + 32768);      // 16 B
  float* partials = (float*)((char*)d_ws + 32768 + 64);   // 3*SUM_BLOCKS f32

  // zero hist + ctl every call (harness doesn't re-poison d_ws)
  hipMemsetAsync(d_ws, 0, 32768 + 64, stream);

  int nvec = N / 4;
  int ntail = N - nvec * 4;

  hist_kernel<<<HIST_BLOCKS, HIST_THREADS, 0, stream>>>(d_curv, hist, nvec, ntail);
  select_kernel<<<1, 256, 0, stream>>>(hist, ctl, K);
  sum_kernel<<<SUM_BLOCKS, SUM_THREADS, 0, stream>>>(d_inputs, d_targets, d_curv,
                                                     ctl, partials, nvec, ntail);
  reduce_kernel<<<1, 1024, 0, stream>>>(partials, out);
}

// Round 6
// 74.439 us; speedup vs baseline: 3.5746x; 1.0912x over previous
//
#include <hip/hip_runtime.h>

#define NB 4096               // 12-bit bins: sign+exp+3 mantissa bits
#define FB_BLOCKS 512
#define FB_THREADS 1024
#define SCALE 32768.0f        // 15-bit fixed point for p, t, p*t
typedef unsigned long long u64;

// Monotone float -> uint map (ascending). Larger curvature -> larger key.
__device__ __forceinline__ unsigned sortable_key(float f) {
  unsigned u = __float_as_uint(f);
  return u ^ ((u & 0x80000000u) ? 0xFFFFFFFFu : 0x80000000u);
}

__device__ __forceinline__ void accum_lds(unsigned* __restrict__ hc,
                                          unsigned* __restrict__ hp,
                                          unsigned* __restrict__ ht,
                                          unsigned* __restrict__ hpt,
                                          float cj, float xj, float tj) {
  unsigned bin = sortable_key(cj) >> 20;
  float p = __fdividef(1.f, 1.f + __expf(-xj));
  unsigned up  = __float2uint_rn(p * SCALE);
  unsigned ut  = __float2uint_rn(tj * SCALE);
  unsigned upt = __float2uint_rn(p * tj * SCALE);
  atomicAdd(&hc[bin], 1u);     // native ds_add_u32
  atomicAdd(&hp[bin], up);
  atomicAdd(&ht[bin], ut);
  atomicAdd(&hpt[bin], upt);
}

// Single pass: per-bin (count, sum_p, sum_t, sum_pt) in u32 LDS, merged to
// global u64 bins. 64 KB LDS -> 2 blocks/CU at 1024 threads (100% occupancy).
__global__ void __launch_bounds__(FB_THREADS, 2) fused_kernel(
    const float* __restrict__ xin, const float* __restrict__ tin,
    const float* __restrict__ cin, u64* __restrict__ g,
    int nvec, int ntail) {
  __shared__ unsigned hc[NB], hp[NB], ht[NB], hpt[NB];
  for (int i = threadIdx.x; i < NB; i += FB_THREADS) {
    hc[i] = 0; hp[i] = 0; ht[i] = 0; hpt[i] = 0;
  }
  __syncthreads();

  const float4* __restrict__ x4 = (const float4*)xin;
  const float4* __restrict__ t4 = (const float4*)tin;
  const float4* __restrict__ c4 = (const float4*)cin;

  int idx = blockIdx.x * FB_THREADS + threadIdx.x;
  int stride = gridDim.x * FB_THREADS;
  int i = idx;
  for (; i + stride < nvec; i += 2 * stride) {  // 6 float4 loads in flight
    float4 c0 = c4[i];
    float4 c1 = c4[i + stride];
    float4 x0 = x4[i];
    float4 x1 = x4[i + stride];
    float4 t0 = t4[i];
    float4 t1 = t4[i + stride];
    accum_lds(hc, hp, ht, hpt, c0.x, x0.x, t0.x);
    accum_lds(hc, hp, ht, hpt, c0.y, x0.y, t0.y);
    accum_lds(hc, hp, ht, hpt, c0.z, x0.z, t0.z);
    accum_lds(hc, hp, ht, hpt, c0.w, x0.w, t0.w);
    accum_lds(hc, hp, ht, hpt, c1.x, x1.x, t1.x);
    accum_lds(hc, hp, ht, hpt, c1.y, x1.y, t1.y);
    accum_lds(hc, hp, ht, hpt, c1.z, x1.z, t1.z);
    accum_lds(hc, hp, ht, hpt, c1.w, x1.w, t1.w);
  }
  for (; i < nvec; i += stride) {
    float4 cv = c4[i], xv = x4[i], tv = t4[i];
    accum_lds(hc, hp, ht, hpt, cv.x, xv.x, tv.x);
    accum_lds(hc, hp, ht, hpt, cv.y, xv.y, tv.y);
    accum_lds(hc, hp, ht, hpt, cv.z, xv.z, tv.z);
    accum_lds(hc, hp, ht, hpt, cv.w, xv.w, tv.w);
  }
  if (idx == 0) {  // scalar tail (N % 4) -> global bins directly
    for (int e = nvec * 4; e < nvec * 4 + ntail; ++e) {
      float cj = cin[e], xj = xin[e], tj = tin[e];
      unsigned bin = sortable_key(cj) >> 20;
      float p = __fdividef(1.f, 1.f + __expf(-xj));
      atomicAdd(&g[bin], (u64)1);
      atomicAdd(&g[NB + bin], (u64)__float2uint_rn(p * SCALE));
      atomicAdd(&g[2 * NB + bin], (u64)__float2uint_rn(tj * SCALE));
      atomicAdd(&g[3 * NB + bin], (u64)__float2uint_rn(p * tj * SCALE));
    }
  }
  __syncthreads();

  // merge nonzero bins (count==0 implies all zero)
  for (int b = threadIdx.x; b < NB; b += FB_THREADS) {
    unsigned cnt = hc[b];
    if (cnt) {
      atomicAdd(&g[b], (u64)cnt);
      atomicAdd(&g[NB + b], (u64)hp[b]);
      atomicAdd(&g[2 * NB + b], (u64)ht[b]);
      atomicAdd(&g[3 * NB + b], (u64)hpt[b]);
    }
  }
}

// One block, 1024 threads x 4 bins: suffix-scan counts from the top to find
// the K crossing, then weighted f64 reduction of bin aggregates + dice.
__global__ void __launch_bounds__(1024) final_kernel(
    const u64* __restrict__ g, unsigned K, float* __restrict__ out) {
  __shared__ unsigned waveTot[16];
  __shared__ unsigned waveSuf[16];
  __shared__ unsigned s_bsel;
  __shared__ double s_frac;
  __shared__ double dsum[3][16];

  int tid = threadIdx.x;
  int lane = tid & 63;
  int wid = tid >> 6;

  unsigned base = (unsigned)tid * 4u;
  unsigned c[4];
  unsigned cs = 0;
#pragma unroll
  for (int j = 0; j < 4; ++j) { c[j] = (unsigned)g[base + j]; cs += c[j]; }

  // wave inclusive suffix sum of per-thread chunk totals
  unsigned incl = cs;
#pragma unroll
  for (int off = 1; off < 64; off <<= 1) {
    unsigned o = __shfl_down(incl, off);
    if (lane + off < 64) incl += o;
  }
  if (lane == 0) waveTot[wid] = incl;
  __syncthreads();
  if (tid == 0) {
    unsigned run = 0;
    for (int w = 15; w >= 0; --w) { waveSuf[w] = run; run += waveTot[w]; }
  }
  __syncthreads();

  unsigned run = waveSuf[wid] + (incl - cs);  // count strictly above my chunk
#pragma unroll
  for (int j = 3; j >= 0; --j) {  // high -> low
    unsigned cc = c[j];
    if (cc && run < K && run + cc >= K) {  // unique crossing
      s_bsel = base + (unsigned)j;
      s_frac = (double)(K - run) / (double)cc;
    }
    run += cc;
  }
  __syncthreads();

  unsigned bsel = s_bsel;
  double frac = s_frac;

  double sp = 0, st = 0, spt = 0;
#pragma unroll
  for (int j = 0; j < 4; ++j) {
    unsigned b = base + j;
    double w = (b > bsel) ? 1.0 : ((b == bsel) ? frac : 0.0);
    if (w != 0.0) {
      sp  += w * (double)g[NB + b];
      st  += w * (double)g[2 * NB + b];
      spt += w * (double)g[3 * NB + b];
    }
  }
#pragma unroll
  for (int off = 32; off > 0; off >>= 1) {
    sp  += __shfl_down(sp, off);
    st  += __shfl_down(st, off);
    spt += __shfl_down(spt, off);
  }
  if (lane == 0) { dsum[0][wid] = sp; dsum[1][wid] = st; dsum[2][wid] = spt; }
  __syncthreads();
  if (tid == 0) {
    double A = 0, B = 0, C = 0;
#pragma unroll
    for (int w = 0; w < 16; ++w) { A += dsum[0][w]; B += dsum[1][w]; C += dsum[2][w]; }
    const double inv = 1.0 / (double)SCALE;
    A *= inv; B *= inv; C *= inv;
    double dice = (2.0 * C + 1.0) / (A + B + 1.0);
    out[0] = (float)(1.0 - dice);
  }
}

extern "C" void kernel_launch(void* const* d_in, const int* in_sizes, int n_in,
                              void* d_out, int out_size, void* d_ws, size_t ws_size,
                              hipStream_t stream) {
  const float* d_inputs  = (const float*)d_in[0];
  const float* d_targets = (const float*)d_in[1];
  const float* d_curv    = (const float*)d_in[2];
  float* out = (float*)d_out;

  int N = in_sizes[2];
  unsigned K = (unsigned)(0.4 * (double)N);  // matches Python int(R*N)

  u64* g = (u64*)d_ws;  // 4 * NB u64 = 128 KB

  // zero global bins every call (harness doesn't re-poison d_ws)
  hipMemsetAsync(d_ws, 0, 4 * NB * sizeof(u64), stream);

  int nvec = N / 4;
  int ntail = N - nvec * 4;

  fused_kernel<<<FB_BLOCKS, FB_THREADS, 0, stream>>>(d_inputs, d_targets,
                                                     d_curv, g, nvec, ntail);
  final_kernel<<<1, 1024, 0, stream>>>(g, K, out);
}